// Round 9
// baseline (74.319 us; speedup 1.0000x reference)
//
#include <hip/hip_runtime.h>
#include <hip/hip_bf16.h>

typedef __attribute__((ext_vector_type(8))) short short8;
typedef __attribute__((ext_vector_type(4))) float f32x4;
typedef __attribute__((ext_vector_type(4))) int int4v;

#define LN_EPS 1e-5f

__device__ __forceinline__ unsigned short bf16rn(float f) {
    unsigned int u = __builtin_bit_cast(unsigned int, f);
    u = u + 0x7fffu + ((u >> 16) & 1u);
    return (unsigned short)(u >> 16);
}

__device__ __forceinline__ unsigned cvt_pk(float lo, float hi) {
    unsigned r;
    asm("v_cvt_pk_bf16_f32 %0, %1, %2" : "=v"(r) : "v"(lo), "v"(hi));
    return r;
}

// ---------------- K0: prep W2->bf16 and W1pad (2048x32 bf16, col8=b1) ----------------
__global__ __launch_bounds__(256) void k_prep(const float* __restrict__ w2,
                                              const float* __restrict__ w1,
                                              const float* __restrict__ b1,
                                              unsigned short* __restrict__ w2b,
                                              unsigned short* __restrict__ w1p) {
    const int bid = blockIdx.x;
    if (bid < 256) {
        int i = (bid * 256 + threadIdx.x) * 4;
        float4 v = *(const float4*)(w2 + i);
        ushort4 r;
        r.x = bf16rn(v.x); r.y = bf16rn(v.y); r.z = bf16rn(v.z); r.w = bf16rn(v.w);
        *(ushort4*)(w2b + i) = r;
    } else {
        int f = (bid - 256) * 256 + threadIdx.x;  // 0..2047
        float4 wa = *(const float4*)(w1 + (size_t)f * 8);
        float4 wb = *(const float4*)(w1 + (size_t)f * 8 + 4);
        short8 r0, r1;
        r0[0] = (short)bf16rn(wa.x); r0[1] = (short)bf16rn(wa.y);
        r0[2] = (short)bf16rn(wa.z); r0[3] = (short)bf16rn(wa.w);
        r0[4] = (short)bf16rn(wb.x); r0[5] = (short)bf16rn(wb.y);
        r0[6] = (short)bf16rn(wb.z); r0[7] = (short)bf16rn(wb.w);
        r1 = short8{0, 0, 0, 0, 0, 0, 0, 0};
        r1[0] = (short)bf16rn(b1[f]);  // multiplied by qpad[8]=1.0
        short8 z = short8{0, 0, 0, 0, 0, 0, 0, 0};
        unsigned short* row = w1p + (size_t)f * 32;
        *(short8*)(row) = r0;
        *(short8*)(row + 8) = r1;
        *(short8*)(row + 16) = z;
        *(short8*)(row + 24) = z;
    }
}

// ---------------- K1: attn + LN1 -> x1 (=d_out), qpad (bf16, K=32 padded) ----------------
__global__ __launch_bounds__(256) void k_pre(const float* __restrict__ x,
                                             const float* __restrict__ theta,
                                             const float* __restrict__ phi,
                                             const float* __restrict__ gamma1,
                                             const float* __restrict__ beta1,
                                             float* __restrict__ x1,
                                             unsigned short* __restrict__ qpad) {
    const int tid = threadIdx.x;
    const int g = tid >> 4, li = tid & 15;
    const int tok = blockIdx.x * 16 + g;

    const float* xr = x + (size_t)tok * 128 + li * 8;
    float4 va = *(const float4*)xr;
    float4 vb = *(const float4*)(xr + 4);
    float v[8] = {va.x, va.y, va.z, va.w, vb.x, vb.y, vb.z, vb.w};

    float c[8];
#pragma unroll
    for (int k = 0; k < 8; ++k) c[k] = __cosf(v[k] + theta[k]);
    float cp[8];
    cp[0] = c[0];
#pragma unroll
    for (int k = 1; k < 8; ++k) cp[k] = cp[k - 1] * c[k];

    float y[8];
    y[0] = v[0] + cp[7];
#pragma unroll
    for (int k = 1; k < 8; ++k) y[k] = v[k] + cp[k];

    float s1 = 0.f, s2 = 0.f;
#pragma unroll
    for (int k = 0; k < 8; ++k) { s1 += y[k]; s2 += y[k] * y[k]; }
#pragma unroll
    for (int m = 1; m < 16; m <<= 1) {
        s1 += __shfl_xor(s1, m);
        s2 += __shfl_xor(s2, m);
    }
    float mean = s1 * (1.f / 128.f);
    float var = s2 * (1.f / 128.f) - mean * mean;
    float rs = rsqrtf(var + LN_EPS);

    float4 ga = *(const float4*)(gamma1 + li * 8);
    float4 gb = *(const float4*)(gamma1 + li * 8 + 4);
    float4 ba = *(const float4*)(beta1 + li * 8);
    float4 bb = *(const float4*)(beta1 + li * 8 + 4);
    float gam[8] = {ga.x, ga.y, ga.z, ga.w, gb.x, gb.y, gb.z, gb.w};
    float bet[8] = {ba.x, ba.y, ba.z, ba.w, bb.x, bb.y, bb.z, bb.w};

    float o[8];
#pragma unroll
    for (int k = 0; k < 8; ++k) o[k] = (y[k] - mean) * rs * gam[k] + bet[k];

    float* x1r = x1 + (size_t)tok * 128 + li * 8;
    *(float4*)x1r = make_float4(o[0], o[1], o[2], o[3]);
    *(float4*)(x1r + 4) = make_float4(o[4], o[5], o[6], o[7]);

    // qpad row: [q0..q7, 1.0, 0...0] in bf16 (32 elems)
    if (li == 0) {
        short8 qr;
#pragma unroll
        for (int k = 0; k < 8; ++k)
            qr[k] = (short)bf16rn(__cosf(phi[k]) * __cosf(o[k]));
        *(short8*)(qpad + (size_t)tok * 32) = qr;
    } else if (li < 4) {
        short8 z = short8{0, 0, 0, 0, 0, 0, 0, 0};
        if (li == 1) z[0] = (short)0x3F80;  // 1.0bf16 -> picks up b1 column
        *(short8*)(qpad + (size_t)tok * 32 + li * 8) = z;
    }
}

// ---------------- K2: fused FFN, full-K waves, 4 blocks/CU ----------------
// Block = 4 waves (256 thr) = nh(2 col-halves) x mw(2 token-groups); 32 tokens;
// grid 1024 -> 4 blocks/CU (33 KB LDS), 16 waves/CU. No split-K: each wave
// owns 16 tokens x 64 cols x full K=2048 -> no reduction buffer, block-local
// barriers overlap across the 4 independent blocks per CU.
// Staging/swizzle is R7's proven BK=64 pattern verbatim (measured 0 conflicts):
// Bs row stride 64 elems (128 B), chunk ^= row&7, pre-swizzled global source.
// GEMM1 h=relu(q*W1pad^T) on MFMA, permuted A-rows -> output IS GEMM2 A-frag.
__global__ __launch_bounds__(256, 4) void k_ffn(const float* __restrict__ x1,
                                                const unsigned short* __restrict__ qpad,
                                                const unsigned short* __restrict__ w2b,
                                                const unsigned short* __restrict__ w1p,
                                                const float* __restrict__ b2,
                                                const float* __restrict__ g2,
                                                const float* __restrict__ be2,
                                                float* __restrict__ out) {
    const int tid = threadIdx.x;
    const int wv = tid >> 6;       // 0..3
    const int nh = wv & 1;         // col-half
    const int mw = wv >> 1;        // token-group
    const int lane = tid & 63;
    const int li = lane & 15;
    const int lg = lane >> 4;
    const int Tb = blockIdx.x * 32;
    const int t0 = Tb + mw * 16;   // wave token base (1 M-tile)

    __shared__ __align__(16) unsigned short Bs[2][128 * 64];  // [buf][row*64+k]
    __shared__ float sums[32][4];  // per-token {s1,s2} x {nh0,nh1}

    // q fragment (k-invariant)
    short8 qf = *(const short8*)(qpad + (size_t)(t0 + li) * 32 + lg * 8);

    // GEMM1 A-row offset (elements); m=1 adds 4*32=128
    const int arow0 = (8 * (li >> 2) + (li & 3)) * 32 + lg * 8;

    f32x4 acc[4];
#pragma unroll
    for (int nt = 0; nt < 4; ++nt) acc[nt] = f32x4{0.f, 0.f, 0.f, 0.f};

    // staging lane constants (R7 pattern): lane covers (row = e0 + lane/8, chunk = lane%8)
    const int srow = lane >> 3;
    const int scs = (lane & 7) ^ srow;  // pre-swizzled source chunk

    auto stage = [&](int buf, int kb) {
#pragma unroll
        for (int r = 0; r < 4; ++r) {
            const int e0 = r * 32 + wv * 8;  // wave-uniform row base
            const unsigned short* src =
                w2b + (size_t)(e0 + srow) * 2048 + kb + scs * 8;
            unsigned short* dst = &Bs[buf][e0 * 64];
            __builtin_amdgcn_global_load_lds(
                (const __attribute__((address_space(1))) unsigned int*)src,
                (__attribute__((address_space(3))) unsigned int*)dst,
                16, 0, 0);
        }
    };

    stage(0, 0);
    __syncthreads();

    const f32x4 zero4 = f32x4{0.f, 0.f, 0.f, 0.f};

    for (int kbi = 0; kbi < 32; ++kbi) {
        const int buf = kbi & 1;
        if (kbi < 31) stage(buf ^ 1, (kbi + 1) * 64);

#pragma unroll
        for (int kk = 0; kk < 2; ++kk) {
            const int f = kbi * 64 + kk * 32;

            // GEMM1 A-frags (W1pad, permuted rows) — L2-resident global
            const unsigned short* wbase = w1p + (size_t)f * 32;
            short8 A0 = *(const short8*)(wbase + arow0);
            short8 A1 = *(const short8*)(wbase + arow0 + 128);

            // GEMM2 B-frags from LDS: 4 N-tiles, single base + imm offsets
            const int cs = (kk * 4 + lg) ^ (li & 7);
            const unsigned short* basep = &Bs[buf][(nh * 64 + li) * 64 + cs * 8];
            short8 bfr[4];
#pragma unroll
            for (int nt = 0; nt < 4; ++nt)
                bfr[nt] = *(const short8*)(basep + nt * 1024);

            // GEMM1 -> relu -> pack -> GEMM2
            f32x4 p0 = __builtin_amdgcn_mfma_f32_16x16x32_bf16(A0, qf, zero4, 0, 0, 0);
            f32x4 p1 = __builtin_amdgcn_mfma_f32_16x16x32_bf16(A1, qf, zero4, 0, 0, 0);
#pragma unroll
            for (int r = 0; r < 4; ++r) {
                p0[r] = fmaxf(p0[r], 0.f);
                p1[r] = fmaxf(p1[r], 0.f);
            }
            int4v ai = {(int)cvt_pk(p0[0], p0[1]), (int)cvt_pk(p0[2], p0[3]),
                        (int)cvt_pk(p1[0], p1[1]), (int)cvt_pk(p1[2], p1[3])};
            short8 a2 = __builtin_bit_cast(short8, ai);
#pragma unroll
            for (int nt = 0; nt < 4; ++nt)
                acc[nt] = __builtin_amdgcn_mfma_f32_16x16x32_bf16(a2, bfr[nt], acc[nt], 0, 0, 0);
        }
        __syncthreads();
    }

    // ---- epilogue: +b2, +x1 residual, cross-nh LN2 via sums ----
    float b2v[4], g2v[4], be2v[4];
#pragma unroll
    for (int nt = 0; nt < 4; ++nt) {
        int e = nh * 64 + nt * 16 + li;
        b2v[nt] = b2[e]; g2v[nt] = g2[e]; be2v[nt] = be2[e];
    }

#pragma unroll
    for (int r = 0; r < 4; ++r) {
        const int ltok = mw * 16 + lg * 4 + r;
        const int tok = Tb + ltok;
        const float* x1r = x1 + (size_t)tok * 128 + nh * 64 + li;
        float s1 = 0.f, s2 = 0.f;
#pragma unroll
        for (int nt = 0; nt < 4; ++nt) {
            float v = acc[nt][r] + b2v[nt] + x1r[nt * 16];
            acc[nt][r] = v;
            s1 += v; s2 += v * v;
        }
#pragma unroll
        for (int m = 1; m < 16; m <<= 1) {
            s1 += __shfl_xor(s1, m);
            s2 += __shfl_xor(s2, m);
        }
        if (li == 0) {
            sums[ltok][nh * 2 + 0] = s1;
            sums[ltok][nh * 2 + 1] = s2;
        }
    }
    __syncthreads();

#pragma unroll
    for (int r = 0; r < 4; ++r) {
        const int ltok = mw * 16 + lg * 4 + r;
        const int tok = Tb + ltok;
        float s1 = sums[ltok][0] + sums[ltok][2];
        float s2 = sums[ltok][1] + sums[ltok][3];
        float mean = s1 * (1.f / 128.f);
        float var = s2 * (1.f / 128.f) - mean * mean;
        float rs = rsqrtf(var + LN_EPS);
        float* orow = out + (size_t)tok * 128 + nh * 64 + li;
#pragma unroll
        for (int nt = 0; nt < 4; ++nt)
            orow[nt * 16] = (acc[nt][r] - mean) * rs * g2v[nt] + be2v[nt];
    }
}

extern "C" void kernel_launch(void* const* d_in, const int* in_sizes, int n_in,
                              void* d_out, int out_size, void* d_ws, size_t ws_size,
                              hipStream_t stream) {
    const float* x      = (const float*)d_in[0];
    const float* theta  = (const float*)d_in[1];
    const float* phi    = (const float*)d_in[2];
    const float* w1     = (const float*)d_in[3];
    const float* b1     = (const float*)d_in[4];
    const float* w2     = (const float*)d_in[5];
    const float* b2     = (const float*)d_in[6];
    const float* gamma1 = (const float*)d_in[7];
    const float* beta1  = (const float*)d_in[8];
    const float* gamma2 = (const float*)d_in[9];
    const float* beta2  = (const float*)d_in[10];
    float* out = (float*)d_out;

    char* ws = (char*)d_ws;
    unsigned short* w2b  = (unsigned short*)ws;                  // 512 KB
    unsigned short* w1p  = (unsigned short*)(ws + (512 << 10));  // 128 KB
    unsigned short* qpad = (unsigned short*)(ws + (1 << 20));    // 2 MB

    k_prep<<<264, 256, 0, stream>>>(w2, w1, b1, w2b, w1p);
    k_pre<<<2048, 256, 0, stream>>>(x, theta, phi, gamma1, beta1, out, qpad);
    k_ffn<<<1024, 256, 0, stream>>>(out, qpad, w2b, w1p, b2, gamma2, beta2, out);
}

// Round 10
// 58.161 us; speedup vs baseline: 1.2778x; 1.2778x over previous
//
#include <hip/hip_runtime.h>
#include <hip/hip_bf16.h>

typedef __attribute__((ext_vector_type(8))) short short8;
typedef __attribute__((ext_vector_type(4))) float f32x4;
typedef __attribute__((ext_vector_type(4))) int int4v;

#define LN_EPS 1e-5f

__device__ __forceinline__ unsigned short bf16rn(float f) {
    unsigned int u = __builtin_bit_cast(unsigned int, f);
    u = u + 0x7fffu + ((u >> 16) & 1u);
    return (unsigned short)(u >> 16);
}

__device__ __forceinline__ unsigned cvt_pk(float lo, float hi) {
    unsigned r;
    asm("v_cvt_pk_bf16_f32 %0, %1, %2" : "=v"(r) : "v"(lo), "v"(hi));
    return r;
}

// ---------------- K0: prep W2->bf16 and W1pad (2048x32 bf16, col8=b1) ----------------
__global__ __launch_bounds__(256) void k_prep(const float* __restrict__ w2,
                                              const float* __restrict__ w1,
                                              const float* __restrict__ b1,
                                              unsigned short* __restrict__ w2b,
                                              unsigned short* __restrict__ w1p) {
    const int bid = blockIdx.x;
    if (bid < 256) {
        int i = (bid * 256 + threadIdx.x) * 4;
        float4 v = *(const float4*)(w2 + i);
        ushort4 r;
        r.x = bf16rn(v.x); r.y = bf16rn(v.y); r.z = bf16rn(v.z); r.w = bf16rn(v.w);
        *(ushort4*)(w2b + i) = r;
    } else {
        int f = (bid - 256) * 256 + threadIdx.x;  // 0..2047
        float4 wa = *(const float4*)(w1 + (size_t)f * 8);
        float4 wb = *(const float4*)(w1 + (size_t)f * 8 + 4);
        short8 r0, r1;
        r0[0] = (short)bf16rn(wa.x); r0[1] = (short)bf16rn(wa.y);
        r0[2] = (short)bf16rn(wa.z); r0[3] = (short)bf16rn(wa.w);
        r0[4] = (short)bf16rn(wb.x); r0[5] = (short)bf16rn(wb.y);
        r0[6] = (short)bf16rn(wb.z); r0[7] = (short)bf16rn(wb.w);
        r1 = short8{0, 0, 0, 0, 0, 0, 0, 0};
        r1[0] = (short)bf16rn(b1[f]);  // multiplied by qpad[8]=1.0
        short8 z = short8{0, 0, 0, 0, 0, 0, 0, 0};
        unsigned short* row = w1p + (size_t)f * 32;
        *(short8*)(row) = r0;
        *(short8*)(row + 8) = r1;
        *(short8*)(row + 16) = z;
        *(short8*)(row + 24) = z;
    }
}

// ---------------- K1: attn + LN1 -> x1 (=d_out), qpad (bf16, K=32 padded) ----------------
__global__ __launch_bounds__(256) void k_pre(const float* __restrict__ x,
                                             const float* __restrict__ theta,
                                             const float* __restrict__ phi,
                                             const float* __restrict__ gamma1,
                                             const float* __restrict__ beta1,
                                             float* __restrict__ x1,
                                             unsigned short* __restrict__ qpad) {
    const int tid = threadIdx.x;
    const int g = tid >> 4, li = tid & 15;
    const int tok = blockIdx.x * 16 + g;

    const float* xr = x + (size_t)tok * 128 + li * 8;
    float4 va = *(const float4*)xr;
    float4 vb = *(const float4*)(xr + 4);
    float v[8] = {va.x, va.y, va.z, va.w, vb.x, vb.y, vb.z, vb.w};

    float c[8];
#pragma unroll
    for (int k = 0; k < 8; ++k) c[k] = __cosf(v[k] + theta[k]);
    float cp[8];
    cp[0] = c[0];
#pragma unroll
    for (int k = 1; k < 8; ++k) cp[k] = cp[k - 1] * c[k];

    float y[8];
    y[0] = v[0] + cp[7];
#pragma unroll
    for (int k = 1; k < 8; ++k) y[k] = v[k] + cp[k];

    float s1 = 0.f, s2 = 0.f;
#pragma unroll
    for (int k = 0; k < 8; ++k) { s1 += y[k]; s2 += y[k] * y[k]; }
#pragma unroll
    for (int m = 1; m < 16; m <<= 1) {
        s1 += __shfl_xor(s1, m);
        s2 += __shfl_xor(s2, m);
    }
    float mean = s1 * (1.f / 128.f);
    float var = s2 * (1.f / 128.f) - mean * mean;
    float rs = rsqrtf(var + LN_EPS);

    float4 ga = *(const float4*)(gamma1 + li * 8);
    float4 gb = *(const float4*)(gamma1 + li * 8 + 4);
    float4 ba = *(const float4*)(beta1 + li * 8);
    float4 bb = *(const float4*)(beta1 + li * 8 + 4);
    float gam[8] = {ga.x, ga.y, ga.z, ga.w, gb.x, gb.y, gb.z, gb.w};
    float bet[8] = {ba.x, ba.y, ba.z, ba.w, bb.x, bb.y, bb.z, bb.w};

    float o[8];
#pragma unroll
    for (int k = 0; k < 8; ++k) o[k] = (y[k] - mean) * rs * gam[k] + bet[k];

    float* x1r = x1 + (size_t)tok * 128 + li * 8;
    *(float4*)x1r = make_float4(o[0], o[1], o[2], o[3]);
    *(float4*)(x1r + 4) = make_float4(o[4], o[5], o[6], o[7]);

    // qpad row: [q0..q7, 1.0, 0...0] in bf16 (32 elems)
    if (li == 0) {
        short8 qr;
#pragma unroll
        for (int k = 0; k < 8; ++k)
            qr[k] = (short)bf16rn(__cosf(phi[k]) * __cosf(o[k]));
        *(short8*)(qpad + (size_t)tok * 32) = qr;
    } else if (li < 4) {
        short8 z = short8{0, 0, 0, 0, 0, 0, 0, 0};
        if (li == 1) z[0] = (short)0x3F80;  // 1.0bf16 -> picks up b1 column
        *(short8*)(qpad + (size_t)tok * 32 + li * 8) = z;
    }
}

// ---------------- K2: fused FFN, kh2 x nh2 x mw2, 2 blocks/CU ----------------
// Block = 8 waves (512 thr), 64 tokens; grid 512 -> 2 blocks/CU (66 KB LDS),
// 16 waves/CU (4/SIMD via __launch_bounds__(512,4), VGPR<=128).
// Wave (kh, nh, mw): tokens mw*32..+32 (2 M-tiles), cols nh*64..+64 (4 N-tiles),
// feats kh*1024..+1024. Staging/swizzle = R7's proven BK=64 pattern verbatim
// (0 conflicts measured): Bs row stride 64 elems, chunk ^= row&7, pre-swizzled
// global source. GEMM1 h=relu(q*W1pad^T) on MFMA, permuted A-rows -> output IS
// GEMM2 A-frag. Split-K reduction buffer `red` ALIASES Bs (dead after K-loop,
// 33.8 KB <= 64 KB; barrier-protected).
__global__ __launch_bounds__(512, 4) void k_ffn(const float* __restrict__ x1,
                                                const unsigned short* __restrict__ qpad,
                                                const unsigned short* __restrict__ w2b,
                                                const unsigned short* __restrict__ w1p,
                                                const float* __restrict__ b2,
                                                const float* __restrict__ g2,
                                                const float* __restrict__ be2,
                                                float* __restrict__ out) {
    const int tid = threadIdx.x;
    const int wv = tid >> 6;       // 0..7
    const int kh = wv >> 2;        // K-half
    const int sub = wv & 3;        // wave within K-half
    const int nh = sub & 1;        // col-half
    const int mw = sub >> 1;       // token-group
    const int lane = tid & 63;
    const int li = lane & 15;
    const int lg = lane >> 4;
    const int Tb = blockIdx.x * 64;
    const int lt0 = mw * 32;       // block-local wave token base (2 M-tiles)
    const int t0 = Tb + lt0;       // global wave token base

    __shared__ __align__(16) char smem[65536 + 1024];
    unsigned short* Bs = (unsigned short*)smem;      // [(kh*2+buf)*8192 + row*64 + k]
    float (*red)[132] = (float(*)[132])smem;         // [64][132] aliases Bs (epilogue only)
    float (*sums)[4] = (float(*)[4])(smem + 65536);  // [64][4] per-token {s1,s2} x nh

    // q fragments (k-invariant): 2 M-tiles
    short8 qf[2];
#pragma unroll
    for (int mt = 0; mt < 2; ++mt)
        qf[mt] = *(const short8*)(qpad + (size_t)(t0 + mt * 16 + li) * 32 + lg * 8);

    // GEMM1 A-row offset (elements); m=1 adds 4*32=128
    const int arow0 = (8 * (li >> 2) + (li & 3)) * 32 + lg * 8;

    f32x4 acc[2][4];
#pragma unroll
    for (int mt = 0; mt < 2; ++mt)
#pragma unroll
        for (int nt = 0; nt < 4; ++nt) acc[mt][nt] = f32x4{0.f, 0.f, 0.f, 0.f};

    // staging lane constants (R7 pattern): lane covers (row = e0 + lane/8, chunk = lane%8)
    const int srow = lane >> 3;
    const int scs = (lane & 7) ^ srow;  // pre-swizzled source chunk

    auto stage = [&](int buf, int kb_local) {
        const int kb = kh * 1024 + kb_local;
#pragma unroll
        for (int r = 0; r < 4; ++r) {
            const int e0 = r * 32 + sub * 8;  // wave-uniform row base
            const unsigned short* src =
                w2b + (size_t)(e0 + srow) * 2048 + kb + scs * 8;
            unsigned short* dst = Bs + (kh * 2 + buf) * 8192 + e0 * 64;
            __builtin_amdgcn_global_load_lds(
                (const __attribute__((address_space(1))) unsigned int*)src,
                (__attribute__((address_space(3))) unsigned int*)dst,
                16, 0, 0);
        }
    };

    stage(0, 0);
    __syncthreads();

    const f32x4 zero4 = f32x4{0.f, 0.f, 0.f, 0.f};

    for (int kbi = 0; kbi < 16; ++kbi) {
        const int buf = kbi & 1;
        if (kbi < 15) stage(buf ^ 1, (kbi + 1) * 64);

#pragma unroll
        for (int kk = 0; kk < 2; ++kk) {
            const int f = kh * 1024 + kbi * 64 + kk * 32;

            // GEMM1 A-frags (W1pad, permuted rows) — L2-resident global
            const unsigned short* wbase = w1p + (size_t)f * 32;
            short8 A0 = *(const short8*)(wbase + arow0);
            short8 A1 = *(const short8*)(wbase + arow0 + 128);

            // GEMM2 B-frags from LDS: 4 N-tiles, single base + imm offsets
            const int cs = (kk * 4 + lg) ^ (li & 7);
            const unsigned short* basep =
                Bs + (kh * 2 + buf) * 8192 + (nh * 64 + li) * 64 + cs * 8;
            short8 bfr[4];
#pragma unroll
            for (int nt = 0; nt < 4; ++nt)
                bfr[nt] = *(const short8*)(basep + nt * 1024);

            // 2 independent M-tile chains: GEMM1 -> relu -> pack -> GEMM2
#pragma unroll
            for (int mt = 0; mt < 2; ++mt) {
                f32x4 p0 = __builtin_amdgcn_mfma_f32_16x16x32_bf16(A0, qf[mt], zero4, 0, 0, 0);
                f32x4 p1 = __builtin_amdgcn_mfma_f32_16x16x32_bf16(A1, qf[mt], zero4, 0, 0, 0);
#pragma unroll
                for (int r = 0; r < 4; ++r) {
                    p0[r] = fmaxf(p0[r], 0.f);
                    p1[r] = fmaxf(p1[r], 0.f);
                }
                int4v ai = {(int)cvt_pk(p0[0], p0[1]), (int)cvt_pk(p0[2], p0[3]),
                            (int)cvt_pk(p1[0], p1[1]), (int)cvt_pk(p1[2], p1[3])};
                short8 a2 = __builtin_bit_cast(short8, ai);
#pragma unroll
                for (int nt = 0; nt < 4; ++nt)
                    acc[mt][nt] = __builtin_amdgcn_mfma_f32_16x16x32_bf16(a2, bfr[nt], acc[mt][nt], 0, 0, 0);
            }
        }
        __syncthreads();
    }

    // ---- epilogue: red aliases Bs (all Bs reads completed at final barrier) ----
    if (kh == 1) {
#pragma unroll
        for (int mt = 0; mt < 2; ++mt)
#pragma unroll
            for (int nt = 0; nt < 4; ++nt)
#pragma unroll
                for (int r = 0; r < 4; ++r)
                    red[lt0 + mt * 16 + lg * 4 + r][nh * 64 + nt * 16 + li] = acc[mt][nt][r];
    }
    __syncthreads();

    float b2v[4], g2v[4], be2v[4];
    if (kh == 0) {
#pragma unroll
        for (int nt = 0; nt < 4; ++nt) {
            int e = nh * 64 + nt * 16 + li;
            b2v[nt] = b2[e]; g2v[nt] = g2[e]; be2v[nt] = be2[e];
        }
        // fold partials + b2 + x1 residual; per-token col-half sums
#pragma unroll
        for (int mt = 0; mt < 2; ++mt) {
#pragma unroll
            for (int r = 0; r < 4; ++r) {
                const int ltok = lt0 + mt * 16 + lg * 4 + r;
                const int tok = Tb + ltok;
                const float* x1r = x1 + (size_t)tok * 128 + nh * 64 + li;
                float s1 = 0.f, s2 = 0.f;
#pragma unroll
                for (int nt = 0; nt < 4; ++nt) {
                    float v = acc[mt][nt][r] + red[ltok][nh * 64 + nt * 16 + li] +
                              b2v[nt] + x1r[nt * 16];
                    acc[mt][nt][r] = v;
                    s1 += v; s2 += v * v;
                }
#pragma unroll
                for (int m = 1; m < 16; m <<= 1) {
                    s1 += __shfl_xor(s1, m);
                    s2 += __shfl_xor(s2, m);
                }
                if (li == 0) {
                    sums[ltok][nh * 2 + 0] = s1;
                    sums[ltok][nh * 2 + 1] = s2;
                }
            }
        }
    }
    __syncthreads();

    if (kh == 0) {
#pragma unroll
        for (int mt = 0; mt < 2; ++mt) {
#pragma unroll
            for (int r = 0; r < 4; ++r) {
                const int ltok = lt0 + mt * 16 + lg * 4 + r;
                const int tok = Tb + ltok;
                float s1 = sums[ltok][0] + sums[ltok][2];
                float s2 = sums[ltok][1] + sums[ltok][3];
                float mean = s1 * (1.f / 128.f);
                float var = s2 * (1.f / 128.f) - mean * mean;
                float rs = rsqrtf(var + LN_EPS);
                float* orow = out + (size_t)tok * 128 + nh * 64 + li;
#pragma unroll
                for (int nt = 0; nt < 4; ++nt)
                    orow[nt * 16] = (acc[mt][nt][r] - mean) * rs * g2v[nt] + be2v[nt];
            }
        }
    }
}

extern "C" void kernel_launch(void* const* d_in, const int* in_sizes, int n_in,
                              void* d_out, int out_size, void* d_ws, size_t ws_size,
                              hipStream_t stream) {
    const float* x      = (const float*)d_in[0];
    const float* theta  = (const float*)d_in[1];
    const float* phi    = (const float*)d_in[2];
    const float* w1     = (const float*)d_in[3];
    const float* b1     = (const float*)d_in[4];
    const float* w2     = (const float*)d_in[5];
    const float* b2     = (const float*)d_in[6];
    const float* gamma1 = (const float*)d_in[7];
    const float* beta1  = (const float*)d_in[8];
    const float* gamma2 = (const float*)d_in[9];
    const float* beta2  = (const float*)d_in[10];
    float* out = (float*)d_out;

    char* ws = (char*)d_ws;
    unsigned short* w2b  = (unsigned short*)ws;                  // 512 KB
    unsigned short* w1p  = (unsigned short*)(ws + (512 << 10));  // 128 KB
    unsigned short* qpad = (unsigned short*)(ws + (1 << 20));    // 2 MB

    k_prep<<<264, 256, 0, stream>>>(w2, w1, b1, w2b, w1p);
    k_pre<<<2048, 256, 0, stream>>>(x, theta, phi, gamma1, beta1, out, qpad);
    k_ffn<<<512, 512, 0, stream>>>(out, qpad, w2b, w1p, b2, gamma2, beta2, out);
}

// Round 11
// 51.038 us; speedup vs baseline: 1.4561x; 1.1396x over previous
//
#include <hip/hip_runtime.h>
#include <hip/hip_bf16.h>

typedef __attribute__((ext_vector_type(8))) short short8;
typedef __attribute__((ext_vector_type(4))) float f32x4;
typedef __attribute__((ext_vector_type(4))) int int4v;

#define LN_EPS 1e-5f

__device__ __forceinline__ unsigned short bf16rn(float f) {
    unsigned int u = __builtin_bit_cast(unsigned int, f);
    u = u + 0x7fffu + ((u >> 16) & 1u);
    return (unsigned short)(u >> 16);
}

__device__ __forceinline__ unsigned cvt_pk(float lo, float hi) {
    unsigned r;
    asm("v_cvt_pk_bf16_f32 %0, %1, %2" : "=v"(r) : "v"(lo), "v"(hi));
    return r;
}

// ---------------- K1: fused {attn+LN1 -> x1,qpad} + {W2->bf16, W1pad prep} ----------------
// bid < 2048: pre (16 tokens/block). bid >= 2048: prep (W2 cvt / W1pad build).
__global__ __launch_bounds__(256) void k_pre(const float* __restrict__ x,
                                             const float* __restrict__ theta,
                                             const float* __restrict__ phi,
                                             const float* __restrict__ gamma1,
                                             const float* __restrict__ beta1,
                                             const float* __restrict__ w1,
                                             const float* __restrict__ b1,
                                             const float* __restrict__ w2,
                                             float* __restrict__ x1,
                                             unsigned short* __restrict__ qpad,
                                             unsigned short* __restrict__ w2b,
                                             unsigned short* __restrict__ w1p) {
    const int tid = threadIdx.x;
    const int bid = blockIdx.x;

    if (bid >= 2048) {  // ---- prep part ----
        const int pid = bid - 2048;
        if (pid < 256) {
            int i = (pid * 256 + tid) * 4;
            float4 v = *(const float4*)(w2 + i);
            ushort4 r;
            r.x = bf16rn(v.x); r.y = bf16rn(v.y); r.z = bf16rn(v.z); r.w = bf16rn(v.w);
            *(ushort4*)(w2b + i) = r;
        } else {
            int f = (pid - 256) * 256 + tid;  // 0..2047
            float4 wa = *(const float4*)(w1 + (size_t)f * 8);
            float4 wb = *(const float4*)(w1 + (size_t)f * 8 + 4);
            short8 r0, r1;
            r0[0] = (short)bf16rn(wa.x); r0[1] = (short)bf16rn(wa.y);
            r0[2] = (short)bf16rn(wa.z); r0[3] = (short)bf16rn(wa.w);
            r0[4] = (short)bf16rn(wb.x); r0[5] = (short)bf16rn(wb.y);
            r0[6] = (short)bf16rn(wb.z); r0[7] = (short)bf16rn(wb.w);
            r1 = short8{0, 0, 0, 0, 0, 0, 0, 0};
            r1[0] = (short)bf16rn(b1[f]);  // multiplied by qpad[8]=1.0
            short8 z = short8{0, 0, 0, 0, 0, 0, 0, 0};
            unsigned short* row = w1p + (size_t)f * 32;
            *(short8*)(row) = r0;
            *(short8*)(row + 8) = r1;
            *(short8*)(row + 16) = z;
            *(short8*)(row + 24) = z;
        }
        return;
    }

    // ---- pre part: attn + LN1 ----
    const int g = tid >> 4, li = tid & 15;
    const int tok = bid * 16 + g;

    const float* xr = x + (size_t)tok * 128 + li * 8;
    float4 va = *(const float4*)xr;
    float4 vb = *(const float4*)(xr + 4);
    float v[8] = {va.x, va.y, va.z, va.w, vb.x, vb.y, vb.z, vb.w};

    float c[8];
#pragma unroll
    for (int k = 0; k < 8; ++k) c[k] = __cosf(v[k] + theta[k]);
    float cp[8];
    cp[0] = c[0];
#pragma unroll
    for (int k = 1; k < 8; ++k) cp[k] = cp[k - 1] * c[k];

    float y[8];
    y[0] = v[0] + cp[7];
#pragma unroll
    for (int k = 1; k < 8; ++k) y[k] = v[k] + cp[k];

    float s1 = 0.f, s2 = 0.f;
#pragma unroll
    for (int k = 0; k < 8; ++k) { s1 += y[k]; s2 += y[k] * y[k]; }
#pragma unroll
    for (int m = 1; m < 16; m <<= 1) {
        s1 += __shfl_xor(s1, m);
        s2 += __shfl_xor(s2, m);
    }
    float mean = s1 * (1.f / 128.f);
    float var = s2 * (1.f / 128.f) - mean * mean;
    float rs = rsqrtf(var + LN_EPS);

    float4 ga = *(const float4*)(gamma1 + li * 8);
    float4 gb = *(const float4*)(gamma1 + li * 8 + 4);
    float4 ba = *(const float4*)(beta1 + li * 8);
    float4 bb = *(const float4*)(beta1 + li * 8 + 4);
    float gam[8] = {ga.x, ga.y, ga.z, ga.w, gb.x, gb.y, gb.z, gb.w};
    float bet[8] = {ba.x, ba.y, ba.z, ba.w, bb.x, bb.y, bb.z, bb.w};

    float o[8];
#pragma unroll
    for (int k = 0; k < 8; ++k) o[k] = (y[k] - mean) * rs * gam[k] + bet[k];

    float* x1r = x1 + (size_t)tok * 128 + li * 8;
    *(float4*)x1r = make_float4(o[0], o[1], o[2], o[3]);
    *(float4*)(x1r + 4) = make_float4(o[4], o[5], o[6], o[7]);

    // qpad row: [q0..q7, 1.0, 0...0] in bf16 (32 elems)
    if (li == 0) {
        short8 qr;
#pragma unroll
        for (int k = 0; k < 8; ++k)
            qr[k] = (short)bf16rn(__cosf(phi[k]) * __cosf(o[k]));
        *(short8*)(qpad + (size_t)tok * 32) = qr;
    } else if (li < 4) {
        short8 z = short8{0, 0, 0, 0, 0, 0, 0, 0};
        if (li == 1) z[0] = (short)0x3F80;  // 1.0bf16 -> picks up b1 column
        *(short8*)(qpad + (size_t)tok * 32 + li * 8) = z;
    }
}

// ---------------- K2: fused FFN, counted-vmcnt pipeline (no barrier drain) ----------------
// Geometry = R10 (proven): 8 waves (512 thr) = kh2 x nh2 x mw2, 64 tokens/block,
// grid 512 -> 2 blocks/CU. Per-iter pipeline (FIFO per wave: A(kbi), stage(kbi), A(kbi+1)):
//   1. prefetch A(kbi+1) -> regs          (keeps pipe deep)
//   2. s_waitcnt vmcnt(4)                 (stage(kbi)+A(kbi) done; A(kbi+1) stays in flight)
//   3. s_barrier + sched_barrier          (all waves' stage(kbi) visible; never drains)
//   4. stage(kbi+1) -> Bs[buf^1]          (race-free after barrier; hides under compute)
//   5. compute kbi from Bs[buf] + A regs
__global__ __launch_bounds__(512, 4) void k_ffn(const float* __restrict__ x1,
                                                const unsigned short* __restrict__ qpad,
                                                const unsigned short* __restrict__ w2b,
                                                const unsigned short* __restrict__ w1p,
                                                const float* __restrict__ b2,
                                                const float* __restrict__ g2,
                                                const float* __restrict__ be2,
                                                float* __restrict__ out) {
    const int tid = threadIdx.x;
    const int wv = tid >> 6;       // 0..7
    const int kh = wv >> 2;        // K-half
    const int sub = wv & 3;        // wave within K-half
    const int nh = sub & 1;        // col-half
    const int mw = sub >> 1;       // token-group
    const int lane = tid & 63;
    const int li = lane & 15;
    const int lg = lane >> 4;
    const int Tb = blockIdx.x * 64;
    const int lt0 = mw * 32;       // block-local wave token base (2 M-tiles)
    const int t0 = Tb + lt0;       // global wave token base

    __shared__ __align__(16) char smem[65536 + 1024];
    unsigned short* Bs = (unsigned short*)smem;      // [(kh*2+buf)*8192 + row*64 + k]
    float (*red)[132] = (float(*)[132])smem;         // [64][132] aliases Bs (epilogue only)
    float (*sums)[4] = (float(*)[4])(smem + 65536);  // [64][4] per-token {s1,s2} x nh

    // q fragments (k-invariant): 2 M-tiles
    short8 qf[2];
#pragma unroll
    for (int mt = 0; mt < 2; ++mt)
        qf[mt] = *(const short8*)(qpad + (size_t)(t0 + mt * 16 + li) * 32 + lg * 8);

    // GEMM1 A-row offset (elements); m=1 adds 4*32=128
    const int arow0 = (8 * (li >> 2) + (li & 3)) * 32 + lg * 8;

    f32x4 acc[2][4];
#pragma unroll
    for (int mt = 0; mt < 2; ++mt)
#pragma unroll
        for (int nt = 0; nt < 4; ++nt) acc[mt][nt] = f32x4{0.f, 0.f, 0.f, 0.f};

    // staging lane constants (R7 pattern, 0 conflicts measured)
    const int srow = lane >> 3;
    const int scs = (lane & 7) ^ srow;  // pre-swizzled source chunk

    auto stage = [&](int buf, int kb_local) {
        const int kb = kh * 1024 + kb_local;
#pragma unroll
        for (int r = 0; r < 4; ++r) {
            const int e0 = r * 32 + sub * 8;  // wave-uniform row base
            const unsigned short* src =
                w2b + (size_t)(e0 + srow) * 2048 + kb + scs * 8;
            unsigned short* dst = Bs + (kh * 2 + buf) * 8192 + e0 * 64;
            __builtin_amdgcn_global_load_lds(
                (const __attribute__((address_space(1))) unsigned int*)src,
                (__attribute__((address_space(3))) unsigned int*)dst,
                16, 0, 0);
        }
    };

    short8 Areg[2][4];  // [phase][kk*2+m]; full unroll -> static indexing
    auto loadA = [&](int kbi_, short8* dst) {
#pragma unroll
        for (int kk = 0; kk < 2; ++kk)
#pragma unroll
            for (int m = 0; m < 2; ++m)
                dst[kk * 2 + m] = *(const short8*)(
                    w1p + (size_t)(kh * 1024 + kbi_ * 64 + kk * 32) * 32 + arow0 + m * 128);
    };

    // prologue: FIFO = qf, A(0), stage(0)
    loadA(0, Areg[0]);
    stage(0, 0);

    const f32x4 zero4 = f32x4{0.f, 0.f, 0.f, 0.f};

#pragma unroll
    for (int kbi = 0; kbi < 16; ++kbi) {
        const int pcur = kbi & 1;
        const int pnext = pcur ^ 1;

        if (kbi < 15) {
            loadA(kbi + 1, Areg[pnext]);                      // A(kbi+1) in flight
            asm volatile("s_waitcnt vmcnt(4)" ::: "memory");  // stage(kbi)+A(kbi) done
        } else {
            asm volatile("s_waitcnt vmcnt(0)" ::: "memory");
        }
        __builtin_amdgcn_s_barrier();
        __builtin_amdgcn_sched_barrier(0);
        if (kbi < 15) stage(pnext, (kbi + 1) * 64);  // after barrier: race-free

#pragma unroll
        for (int kk = 0; kk < 2; ++kk) {
            short8 A0 = Areg[pcur][kk * 2 + 0];
            short8 A1 = Areg[pcur][kk * 2 + 1];

            // GEMM2 B-frags from LDS: 4 N-tiles, single base + imm offsets
            const int cs = (kk * 4 + lg) ^ (li & 7);
            const unsigned short* basep =
                Bs + (kh * 2 + pcur) * 8192 + (nh * 64 + li) * 64 + cs * 8;
            short8 bfr[4];
#pragma unroll
            for (int nt = 0; nt < 4; ++nt)
                bfr[nt] = *(const short8*)(basep + nt * 1024);

            // 2 independent M-tile chains: GEMM1 -> relu -> pack -> GEMM2
#pragma unroll
            for (int mt = 0; mt < 2; ++mt) {
                f32x4 p0 = __builtin_amdgcn_mfma_f32_16x16x32_bf16(A0, qf[mt], zero4, 0, 0, 0);
                f32x4 p1 = __builtin_amdgcn_mfma_f32_16x16x32_bf16(A1, qf[mt], zero4, 0, 0, 0);
#pragma unroll
                for (int r = 0; r < 4; ++r) {
                    p0[r] = fmaxf(p0[r], 0.f);
                    p1[r] = fmaxf(p1[r], 0.f);
                }
                int4v ai = {(int)cvt_pk(p0[0], p0[1]), (int)cvt_pk(p0[2], p0[3]),
                            (int)cvt_pk(p1[0], p1[1]), (int)cvt_pk(p1[2], p1[3])};
                short8 a2 = __builtin_bit_cast(short8, ai);
#pragma unroll
                for (int nt = 0; nt < 4; ++nt)
                    acc[mt][nt] = __builtin_amdgcn_mfma_f32_16x16x32_bf16(a2, bfr[nt], acc[mt][nt], 0, 0, 0);
            }
        }
    }
    __syncthreads();  // pipeline done; safe full drain before red aliases Bs

    // ---- epilogue: red aliases Bs ----
    if (kh == 1) {
#pragma unroll
        for (int mt = 0; mt < 2; ++mt)
#pragma unroll
            for (int nt = 0; nt < 4; ++nt)
#pragma unroll
                for (int r = 0; r < 4; ++r)
                    red[lt0 + mt * 16 + lg * 4 + r][nh * 64 + nt * 16 + li] = acc[mt][nt][r];
    }
    __syncthreads();

    float b2v[4], g2v[4], be2v[4];
    if (kh == 0) {
#pragma unroll
        for (int nt = 0; nt < 4; ++nt) {
            int e = nh * 64 + nt * 16 + li;
            b2v[nt] = b2[e]; g2v[nt] = g2[e]; be2v[nt] = be2[e];
        }
#pragma unroll
        for (int mt = 0; mt < 2; ++mt) {
#pragma unroll
            for (int r = 0; r < 4; ++r) {
                const int ltok = lt0 + mt * 16 + lg * 4 + r;
                const int tok = Tb + ltok;
                const float* x1r = x1 + (size_t)tok * 128 + nh * 64 + li;
                float s1 = 0.f, s2 = 0.f;
#pragma unroll
                for (int nt = 0; nt < 4; ++nt) {
                    float v = acc[mt][nt][r] + red[ltok][nh * 64 + nt * 16 + li] +
                              b2v[nt] + x1r[nt * 16];
                    acc[mt][nt][r] = v;
                    s1 += v; s2 += v * v;
                }
#pragma unroll
                for (int m = 1; m < 16; m <<= 1) {
                    s1 += __shfl_xor(s1, m);
                    s2 += __shfl_xor(s2, m);
                }
                if (li == 0) {
                    sums[ltok][nh * 2 + 0] = s1;
                    sums[ltok][nh * 2 + 1] = s2;
                }
            }
        }
    }
    __syncthreads();

    if (kh == 0) {
#pragma unroll
        for (int mt = 0; mt < 2; ++mt) {
#pragma unroll
            for (int r = 0; r < 4; ++r) {
                const int ltok = lt0 + mt * 16 + lg * 4 + r;
                const int tok = Tb + ltok;
                float s1 = sums[ltok][0] + sums[ltok][2];
                float s2 = sums[ltok][1] + sums[ltok][3];
                float mean = s1 * (1.f / 128.f);
                float var = s2 * (1.f / 128.f) - mean * mean;
                float rs = rsqrtf(var + LN_EPS);
                float* orow = out + (size_t)tok * 128 + nh * 64 + li;
#pragma unroll
                for (int nt = 0; nt < 4; ++nt)
                    orow[nt * 16] = (acc[mt][nt][r] - mean) * rs * g2v[nt] + be2v[nt];
            }
        }
    }
}

extern "C" void kernel_launch(void* const* d_in, const int* in_sizes, int n_in,
                              void* d_out, int out_size, void* d_ws, size_t ws_size,
                              hipStream_t stream) {
    const float* x      = (const float*)d_in[0];
    const float* theta  = (const float*)d_in[1];
    const float* phi    = (const float*)d_in[2];
    const float* w1     = (const float*)d_in[3];
    const float* b1     = (const float*)d_in[4];
    const float* w2     = (const float*)d_in[5];
    const float* b2     = (const float*)d_in[6];
    const float* gamma1 = (const float*)d_in[7];
    const float* beta1  = (const float*)d_in[8];
    const float* gamma2 = (const float*)d_in[9];
    const float* beta2  = (const float*)d_in[10];
    float* out = (float*)d_out;

    char* ws = (char*)d_ws;
    unsigned short* w2b  = (unsigned short*)ws;                  // 512 KB
    unsigned short* w1p  = (unsigned short*)(ws + (512 << 10));  // 128 KB
    unsigned short* qpad = (unsigned short*)(ws + (1 << 20));    // 2 MB

    k_pre<<<2312, 256, 0, stream>>>(x, theta, phi, gamma1, beta1, w1, b1, w2,
                                    out, qpad, w2b, w1p);
    k_ffn<<<512, 512, 0, stream>>>(out, qpad, w2b, w1p, b2, gamma2, beta2, out);
}

// Round 12
// 49.370 us; speedup vs baseline: 1.5053x; 1.0338x over previous
//
#include <hip/hip_runtime.h>
#include <hip/hip_bf16.h>

typedef __attribute__((ext_vector_type(8))) short short8;
typedef __attribute__((ext_vector_type(4))) float f32x4;
typedef __attribute__((ext_vector_type(4))) int int4v;

#define LN_EPS 1e-5f

__device__ __forceinline__ unsigned short bf16rn(float f) {
    unsigned int u = __builtin_bit_cast(unsigned int, f);
    u = u + 0x7fffu + ((u >> 16) & 1u);
    return (unsigned short)(u >> 16);
}

__device__ __forceinline__ unsigned cvt_pk(float lo, float hi) {
    unsigned r;
    asm("v_cvt_pk_bf16_f32 %0, %1, %2" : "=v"(r) : "v"(lo), "v"(hi));
    return r;
}

// ---------------- K1: fused {attn+LN1 -> x1,qpad} + {W2->bf16, W1pad prep} ----------------
__global__ __launch_bounds__(256) void k_pre(const float* __restrict__ x,
                                             const float* __restrict__ theta,
                                             const float* __restrict__ phi,
                                             const float* __restrict__ gamma1,
                                             const float* __restrict__ beta1,
                                             const float* __restrict__ w1,
                                             const float* __restrict__ b1,
                                             const float* __restrict__ w2,
                                             float* __restrict__ x1,
                                             unsigned short* __restrict__ qpad,
                                             unsigned short* __restrict__ w2b,
                                             unsigned short* __restrict__ w1p) {
    const int tid = threadIdx.x;
    const int bid = blockIdx.x;

    if (bid >= 2048) {  // ---- prep part ----
        const int pid = bid - 2048;
        if (pid < 256) {
            int i = (pid * 256 + tid) * 4;
            float4 v = *(const float4*)(w2 + i);
            ushort4 r;
            r.x = bf16rn(v.x); r.y = bf16rn(v.y); r.z = bf16rn(v.z); r.w = bf16rn(v.w);
            *(ushort4*)(w2b + i) = r;
        } else {
            int f = (pid - 256) * 256 + tid;  // 0..2047
            float4 wa = *(const float4*)(w1 + (size_t)f * 8);
            float4 wb = *(const float4*)(w1 + (size_t)f * 8 + 4);
            short8 r0, r1;
            r0[0] = (short)bf16rn(wa.x); r0[1] = (short)bf16rn(wa.y);
            r0[2] = (short)bf16rn(wa.z); r0[3] = (short)bf16rn(wa.w);
            r0[4] = (short)bf16rn(wb.x); r0[5] = (short)bf16rn(wb.y);
            r0[6] = (short)bf16rn(wb.z); r0[7] = (short)bf16rn(wb.w);
            r1 = short8{0, 0, 0, 0, 0, 0, 0, 0};
            r1[0] = (short)bf16rn(b1[f]);  // multiplied by qpad[8]=1.0
            short8 z = short8{0, 0, 0, 0, 0, 0, 0, 0};
            unsigned short* row = w1p + (size_t)f * 32;
            *(short8*)(row) = r0;
            *(short8*)(row + 8) = r1;
            *(short8*)(row + 16) = z;
            *(short8*)(row + 24) = z;
        }
        return;
    }

    // ---- pre part: attn + LN1 ----
    const int g = tid >> 4, li = tid & 15;
    const int tok = bid * 16 + g;

    const float* xr = x + (size_t)tok * 128 + li * 8;
    float4 va = *(const float4*)xr;
    float4 vb = *(const float4*)(xr + 4);
    float v[8] = {va.x, va.y, va.z, va.w, vb.x, vb.y, vb.z, vb.w};

    float c[8];
#pragma unroll
    for (int k = 0; k < 8; ++k) c[k] = __cosf(v[k] + theta[k]);
    float cp[8];
    cp[0] = c[0];
#pragma unroll
    for (int k = 1; k < 8; ++k) cp[k] = cp[k - 1] * c[k];

    float y[8];
    y[0] = v[0] + cp[7];
#pragma unroll
    for (int k = 1; k < 8; ++k) y[k] = v[k] + cp[k];

    float s1 = 0.f, s2 = 0.f;
#pragma unroll
    for (int k = 0; k < 8; ++k) { s1 += y[k]; s2 += y[k] * y[k]; }
#pragma unroll
    for (int m = 1; m < 16; m <<= 1) {
        s1 += __shfl_xor(s1, m);
        s2 += __shfl_xor(s2, m);
    }
    float mean = s1 * (1.f / 128.f);
    float var = s2 * (1.f / 128.f) - mean * mean;
    float rs = rsqrtf(var + LN_EPS);

    float4 ga = *(const float4*)(gamma1 + li * 8);
    float4 gb = *(const float4*)(gamma1 + li * 8 + 4);
    float4 ba = *(const float4*)(beta1 + li * 8);
    float4 bb = *(const float4*)(beta1 + li * 8 + 4);
    float gam[8] = {ga.x, ga.y, ga.z, ga.w, gb.x, gb.y, gb.z, gb.w};
    float bet[8] = {ba.x, ba.y, ba.z, ba.w, bb.x, bb.y, bb.z, bb.w};

    float o[8];
#pragma unroll
    for (int k = 0; k < 8; ++k) o[k] = (y[k] - mean) * rs * gam[k] + bet[k];

    float* x1r = x1 + (size_t)tok * 128 + li * 8;
    *(float4*)x1r = make_float4(o[0], o[1], o[2], o[3]);
    *(float4*)(x1r + 4) = make_float4(o[4], o[5], o[6], o[7]);

    // qpad row: [q0..q7, 1.0, 0...0] in bf16 (32 elems)
    if (li == 0) {
        short8 qr;
#pragma unroll
        for (int k = 0; k < 8; ++k)
            qr[k] = (short)bf16rn(__cosf(phi[k]) * __cosf(o[k]));
        *(short8*)(qpad + (size_t)tok * 32) = qr;
    } else if (li < 4) {
        short8 z = short8{0, 0, 0, 0, 0, 0, 0, 0};
        if (li == 1) z[0] = (short)0x3F80;  // 1.0bf16 -> picks up b1 column
        *(short8*)(qpad + (size_t)tok * 32 + li * 8) = z;
    }
}

// ---------------- K2: fused FFN, h-PIPELINED (T15): GEMM1 one kbi ahead ----------------
// Geometry = R10/R11 (proven): 8 waves = kh2 x nh2 x mw2, 64 tokens, grid 512,
// 2 blocks/CU. NEW: GEMM2(kbi) consumes hfrag[kbi&1] written LAST iter, so its
// 16 MFMAs have no dependency on this iter's GEMM1; GEMM1(kbi+1)+relu+cvt fills
// hfrag[(kbi+1)&1] and its MFMA->VALU hazard overlaps GEMM2's MFMA stream.
// Per-iter FIFO: [stage(kbi)] +loadA(kbi+1) | vmcnt(4) | barrier | stage(kbi+1)
// | ds+G2(kbi) | vmcnt(4) (A ready, stage in flight) | G1(kbi+1)->hfrag.
__global__ __launch_bounds__(512, 4) void k_ffn(const float* __restrict__ x1,
                                                const unsigned short* __restrict__ qpad,
                                                const unsigned short* __restrict__ w2b,
                                                const unsigned short* __restrict__ w1p,
                                                const float* __restrict__ b2,
                                                const float* __restrict__ g2,
                                                const float* __restrict__ be2,
                                                float* __restrict__ out) {
    const int tid = threadIdx.x;
    const int wv = tid >> 6;       // 0..7
    const int kh = wv >> 2;        // K-half
    const int sub = wv & 3;        // wave within K-half
    const int nh = sub & 1;        // col-half
    const int mw = sub >> 1;       // token-group
    const int lane = tid & 63;
    const int li = lane & 15;
    const int lg = lane >> 4;
    const int Tb = blockIdx.x * 64;
    const int lt0 = mw * 32;       // block-local wave token base (2 M-tiles)
    const int t0 = Tb + lt0;       // global wave token base

    __shared__ __align__(16) char smem[65536 + 1024];
    unsigned short* Bs = (unsigned short*)smem;      // [(kh*2+buf)*8192 + row*64 + k]
    float (*red)[132] = (float(*)[132])smem;         // [64][132] aliases Bs (epilogue only)
    float (*sums)[4] = (float(*)[4])(smem + 65536);  // [64][4] per-token {s1,s2} x nh

    // q fragments (k-invariant): 2 M-tiles
    short8 qf[2];
#pragma unroll
    for (int mt = 0; mt < 2; ++mt)
        qf[mt] = *(const short8*)(qpad + (size_t)(t0 + mt * 16 + li) * 32 + lg * 8);

    // GEMM1 A-row offset (elements); m=1 adds 4*32=128
    const int arow0 = (8 * (li >> 2) + (li & 3)) * 32 + lg * 8;

    f32x4 acc[2][4];
#pragma unroll
    for (int mt = 0; mt < 2; ++mt)
#pragma unroll
        for (int nt = 0; nt < 4; ++nt) acc[mt][nt] = f32x4{0.f, 0.f, 0.f, 0.f};

    // staging lane constants (R7 pattern, 0 conflicts measured)
    const int srow = lane >> 3;
    const int scs = (lane & 7) ^ srow;  // pre-swizzled source chunk

    auto stage = [&](int buf, int kb_local) {
        const int kb = kh * 1024 + kb_local;
#pragma unroll
        for (int r = 0; r < 4; ++r) {
            const int e0 = r * 32 + sub * 8;  // wave-uniform row base
            const unsigned short* src =
                w2b + (size_t)(e0 + srow) * 2048 + kb + scs * 8;
            unsigned short* dst = Bs + (kh * 2 + buf) * 8192 + e0 * 64;
            __builtin_amdgcn_global_load_lds(
                (const __attribute__((address_space(1))) unsigned int*)src,
                (__attribute__((address_space(3))) unsigned int*)dst,
                16, 0, 0);
        }
    };

    short8 Areg[4];          // A(kbi) fragments [kk*2+m], single-buffered
    short8 hfrag[2][2][2];   // [phase][kk][mt] — static idx via full unroll

    auto loadA = [&](int kbi_) {
#pragma unroll
        for (int kk = 0; kk < 2; ++kk)
#pragma unroll
            for (int m = 0; m < 2; ++m)
                Areg[kk * 2 + m] = *(const short8*)(
                    w1p + (size_t)(kh * 1024 + kbi_ * 64 + kk * 32) * 32 + arow0 + m * 128);
    };

    const f32x4 zero4 = f32x4{0.f, 0.f, 0.f, 0.f};

    auto gemm1 = [&](int phase) {  // h(next) from Areg: 8 MFMA + relu + pack
#pragma unroll
        for (int kk = 0; kk < 2; ++kk)
#pragma unroll
            for (int mt = 0; mt < 2; ++mt) {
                f32x4 p0 = __builtin_amdgcn_mfma_f32_16x16x32_bf16(Areg[kk * 2 + 0], qf[mt], zero4, 0, 0, 0);
                f32x4 p1 = __builtin_amdgcn_mfma_f32_16x16x32_bf16(Areg[kk * 2 + 1], qf[mt], zero4, 0, 0, 0);
#pragma unroll
                for (int r = 0; r < 4; ++r) {
                    p0[r] = fmaxf(p0[r], 0.f);
                    p1[r] = fmaxf(p1[r], 0.f);
                }
                int4v ai = {(int)cvt_pk(p0[0], p0[1]), (int)cvt_pk(p0[2], p0[3]),
                            (int)cvt_pk(p1[0], p1[1]), (int)cvt_pk(p1[2], p1[3])};
                hfrag[phase][kk][mt] = __builtin_bit_cast(short8, ai);
            }
    };

    // ---- prologue: stage(0) + A(0) -> h(0) ----
    stage(0, 0);
    loadA(0);
    asm volatile("s_waitcnt vmcnt(0)" ::: "memory");
    gemm1(0);
    __syncthreads();  // all waves' stage(0) visible

#pragma unroll
    for (int kbi = 0; kbi < 16; ++kbi) {
        const int pcur = kbi & 1;
        const int pnext = pcur ^ 1;

        if (kbi < 15) {
            loadA(kbi + 1);                                   // A(kbi+1) in flight
            asm volatile("s_waitcnt vmcnt(4)" ::: "memory");  // stage(kbi) done
        } else {
            asm volatile("s_waitcnt vmcnt(0)" ::: "memory");
        }
        __builtin_amdgcn_s_barrier();
        __builtin_amdgcn_sched_barrier(0);
        if (kbi < 15) stage(pnext, (kbi + 1) * 64);  // post-barrier: race-free

        // GEMM2(kbi): hfrag[pcur] x Bs[pcur] — independent of this iter's GEMM1
#pragma unroll
        for (int kk = 0; kk < 2; ++kk) {
            const int cs = (kk * 4 + lg) ^ (li & 7);
            const unsigned short* basep =
                Bs + (kh * 2 + pcur) * 8192 + (nh * 64 + li) * 64 + cs * 8;
            short8 bfr[4];
#pragma unroll
            for (int nt = 0; nt < 4; ++nt)
                bfr[nt] = *(const short8*)(basep + nt * 1024);
#pragma unroll
            for (int mt = 0; mt < 2; ++mt)
#pragma unroll
                for (int nt = 0; nt < 4; ++nt)
                    acc[mt][nt] = __builtin_amdgcn_mfma_f32_16x16x32_bf16(
                        hfrag[pcur][kk][mt], bfr[nt], acc[mt][nt], 0, 0, 0);
        }

        // GEMM1(kbi+1) -> hfrag[pnext]; A ready after vmcnt(4) (stage(kbi+1) stays in flight)
        if (kbi < 15) {
            asm volatile("s_waitcnt vmcnt(4)" ::: "memory");
            gemm1(pnext);
        }
    }
    __syncthreads();  // full drain before red aliases Bs

    // ---- epilogue: red aliases Bs ----
    if (kh == 1) {
#pragma unroll
        for (int mt = 0; mt < 2; ++mt)
#pragma unroll
            for (int nt = 0; nt < 4; ++nt)
#pragma unroll
                for (int r = 0; r < 4; ++r)
                    red[lt0 + mt * 16 + lg * 4 + r][nh * 64 + nt * 16 + li] = acc[mt][nt][r];
    }
    __syncthreads();

    float b2v[4], g2v[4], be2v[4];
    if (kh == 0) {
#pragma unroll
        for (int nt = 0; nt < 4; ++nt) {
            int e = nh * 64 + nt * 16 + li;
            b2v[nt] = b2[e]; g2v[nt] = g2[e]; be2v[nt] = be2[e];
        }
#pragma unroll
        for (int mt = 0; mt < 2; ++mt) {
#pragma unroll
            for (int r = 0; r < 4; ++r) {
                const int ltok = lt0 + mt * 16 + lg * 4 + r;
                const int tok = Tb + ltok;
                const float* x1r = x1 + (size_t)tok * 128 + nh * 64 + li;
                float s1 = 0.f, s2 = 0.f;
#pragma unroll
                for (int nt = 0; nt < 4; ++nt) {
                    float v = acc[mt][nt][r] + red[ltok][nh * 64 + nt * 16 + li] +
                              b2v[nt] + x1r[nt * 16];
                    acc[mt][nt][r] = v;
                    s1 += v; s2 += v * v;
                }
#pragma unroll
                for (int m = 1; m < 16; m <<= 1) {
                    s1 += __shfl_xor(s1, m);
                    s2 += __shfl_xor(s2, m);
                }
                if (li == 0) {
                    sums[ltok][nh * 2 + 0] = s1;
                    sums[ltok][nh * 2 + 1] = s2;
                }
            }
        }
    }
    __syncthreads();

    if (kh == 0) {
#pragma unroll
        for (int mt = 0; mt < 2; ++mt) {
#pragma unroll
            for (int r = 0; r < 4; ++r) {
                const int ltok = lt0 + mt * 16 + lg * 4 + r;
                const int tok = Tb + ltok;
                float s1 = sums[ltok][0] + sums[ltok][2];
                float s2 = sums[ltok][1] + sums[ltok][3];
                float mean = s1 * (1.f / 128.f);
                float var = s2 * (1.f / 128.f) - mean * mean;
                float rs = rsqrtf(var + LN_EPS);
                float* orow = out + (size_t)tok * 128 + nh * 64 + li;
#pragma unroll
                for (int nt = 0; nt < 4; ++nt)
                    orow[nt * 16] = (acc[mt][nt][r] - mean) * rs * g2v[nt] + be2v[nt];
            }
        }
    }
}

extern "C" void kernel_launch(void* const* d_in, const int* in_sizes, int n_in,
                              void* d_out, int out_size, void* d_ws, size_t ws_size,
                              hipStream_t stream) {
    const float* x      = (const float*)d_in[0];
    const float* theta  = (const float*)d_in[1];
    const float* phi    = (const float*)d_in[2];
    const float* w1     = (const float*)d_in[3];
    const float* b1     = (const float*)d_in[4];
    const float* w2     = (const float*)d_in[5];
    const float* b2     = (const float*)d_in[6];
    const float* gamma1 = (const float*)d_in[7];
    const float* beta1  = (const float*)d_in[8];
    const float* gamma2 = (const float*)d_in[9];
    const float* beta2  = (const float*)d_in[10];
    float* out = (float*)d_out;

    char* ws = (char*)d_ws;
    unsigned short* w2b  = (unsigned short*)ws;                  // 512 KB
    unsigned short* w1p  = (unsigned short*)(ws + (512 << 10));  // 128 KB
    unsigned short* qpad = (unsigned short*)(ws + (1 << 20));    // 2 MB

    k_pre<<<2312, 256, 0, stream>>>(x, theta, phi, gamma1, beta1, w1, b1, w2,
                                    out, qpad, w2b, w1p);
    k_ffn<<<512, 512, 0, stream>>>(out, qpad, w2b, w1p, b2, gamma2, beta2, out);
}